// Round 3
// baseline (49.996 us; speedup 1.0000x reference)
//
#include <hip/hip_runtime.h>
#include <cstdint>
#include <cmath>

#define NA   10647
#define NBOX 8
#define NCLS 20
#define FEPS 1e-7f

__device__ __constant__ float ANC[9][2] = {
    {116.0f/416.0f,  90.0f/416.0f},
    {156.0f/416.0f, 198.0f/416.0f},
    {373.0f/416.0f, 326.0f/416.0f},
    { 30.0f/416.0f,  61.0f/416.0f},
    { 62.0f/416.0f,  45.0f/416.0f},
    { 59.0f/416.0f, 119.0f/416.0f},
    { 10.0f/416.0f,  13.0f/416.0f},
    { 16.0f/416.0f,  30.0f/416.0f},
    { 33.0f/416.0f,  23.0f/416.0f}};
__device__ __constant__ float FEATS_F[3] = {13.0f, 26.0f, 52.0f};
__device__ __constant__ float LAYOFF_F[3] = {0.0f, 507.0f, 2535.0f};

__device__ __forceinline__ float focal_term(float l, float y) {
    float bce = fmaxf(l, 0.0f) - l * y + log1pf(expf(-fabsf(l)));
    float p   = 1.0f / (1.0f + expf(-l));
    float pt  = y * p + (1.0f - y) * (1.0f - p);
    float af  = y * 0.25f + (1.0f - y) * 0.75f;
    float om  = 1.0f - pt;
    return bce * af * om * om;
}

// focal with y=0, one expf: bce = relu(x)+log1p(e), p = sigmoid(x), term = bce*0.75*p^2
__device__ __forceinline__ float focal0(float x) {
    float e   = expf(-fabsf(x));
    float bce = fmaxf(x, 0.0f) + log1pf(e);
    float inv = 1.0f / (1.0f + e);
    float p   = (x >= 0.0f) ? inv : e * inv;
    return bce * 0.75f * p * p;
}

// -------------- merged kernel: conf blocks [0,CB) + match blocks [CB,CB+B) ---
// Every block finishes with one device-scope atomicAdd(out, partial*scale).
__global__ __launch_bounds__(256) void k_main(
    const float* __restrict__ p, const float* __restrict__ gboxes,
    const int* __restrict__ glabels, const float* __restrict__ ancs,
    const float* __restrict__ fsz, float* __restrict__ out,
    int ntot, int S, int conf_blocks, float scale)
{
    const int bid = blockIdx.x;

    if (bid < conf_blocks) {
        // ---- conf focal over all anchors (y=0 baseline), 3 anchors/thread ----
        const int tid = bid * 256 + threadIdx.x;
        float acc = 0.0f;
        if (tid < S) {
            const int i0 = tid, i1 = tid + S, i2 = tid + 2 * S;
            float x0 = p[(size_t)i0 * 25 + 4];
            float x1 = (i1 < ntot) ? p[(size_t)i1 * 25 + 4] : 0.0f;
            float x2 = (i2 < ntot) ? p[(size_t)i2 * 25 + 4] : 0.0f;
            acc = focal0(x0);
            if (i1 < ntot) acc += focal0(x1);
            if (i2 < ntot) acc += focal0(x2);
        }
        for (int off = 32; off; off >>= 1) acc += __shfl_down(acc, off);
        __shared__ float sred[4];
        if ((threadIdx.x & 63) == 0) sred[threadIdx.x >> 6] = acc;
        __syncthreads();
        if (threadIdx.x == 0)
            atomicAdd(out, (sred[0] + sred[1] + sred[2] + sred[3]) * scale);
        return;
    }

    // ---- per-image matching + cls/box/conf-correction (lanes 0..63 active) ----
    const int b = bid - conf_blocks;
    const int l = threadIdx.x;

    __shared__ float s_g[NBOX][9];        // l,t,r,b,cx,cy,w,h,atan(w/(h+eps))
    __shared__ float s_anc[NBOX][9][4];   // unshifted anchor ltrb per (box,anchor)
    __shared__ float s_cr[NBOX][9][2];    // (col,row) per (box,anchor)
    __shared__ float s_atanA[9];
    __shared__ int   s_match[NBOX];

    if (l < NBOX) {
        const float* gb = gboxes + (size_t)(b * NBOX + l) * 4;
        float gl = gb[0], gt = gb[1], gr = gb[2], gbb = gb[3];
        float cx = (gl + gr) * 0.5f, cy = (gt + gbb) * 0.5f;
        float w = gr - gl, h = gbb - gt;
        s_g[l][0] = gl; s_g[l][1] = gt; s_g[l][2] = gr; s_g[l][3] = gbb;
        s_g[l][4] = cx; s_g[l][5] = cy; s_g[l][6] = w;  s_g[l][7] = h;
        s_g[l][8] = atanf(w / (h + FEPS));
    }
    if (l >= 64 && l < 64 + 9) s_atanA[l - 64] = atanf(ANC[l - 64][0] / (ANC[l - 64][1] + FEPS));
    if (l >= 128 && l < 128 + NBOX * 9) {
        int pair = l - 128;
        int j = pair / 9, k = pair % 9;
        const float* gb = gboxes + (size_t)(b * NBOX + j) * 4;
        float cx = (gb[0] + gb[2]) * 0.5f, cy = (gb[1] + gb[3]) * 0.5f;
        float fs = FEATS_F[k / 3];
        float col = floorf(cx * fs), row = floorf(cy * fs);
        float ax = col / fs, ay = row / fs;
        float aw = ANC[k][0], ah = ANC[k][1];
        s_anc[j][k][0] = ax - aw * 0.5f;
        s_anc[j][k][1] = ay - ah * 0.5f;
        s_anc[j][k][2] = ax + aw * 0.5f;
        s_anc[j][k][3] = ay + ah * 0.5f;
        s_cr[j][k][0] = col; s_cr[j][k][1] = row;
    }
    __syncthreads();

    if (l < 64) {
        const int i = l >> 3, j = l & 7;
        const float fi = (float)i, fj = (float)j;
        float al = s_g[i][0] + fi, at = s_g[i][1] + fi;
        float ar = s_g[i][2] + fi, ab = s_g[i][3] + fi;
        float wa = ar - al, ha = ab - at;
        float cax = (al + ar) * 0.5f, cay = (at + ab) * 0.5f;
        float atg = s_g[i][8];

        float bestv = -1e30f; int besti = 1 << 30;
        #pragma unroll
        for (int k = 0; k < 9; ++k) {
            float bl = s_anc[j][k][0] + fj, bt = s_anc[j][k][1] + fj;
            float br = s_anc[j][k][2] + fj, bb = s_anc[j][k][3] + fj;
            float wb = br - bl, hb = bb - bt;
            float ix = fmaxf(fminf(ar, br) - fmaxf(al, bl), 0.0f);
            float iy = fmaxf(fminf(ab, bb) - fmaxf(at, bt), 0.0f);
            float inter = ix * iy;
            float uni = wa * ha + wb * hb - inter;
            float iou = inter / (uni + FEPS);
            float cw = fmaxf(ar, br) - fminf(al, bl);
            float ch = fmaxf(ab, bb) - fminf(at, bt);
            float c2 = cw * cw + ch * ch + FEPS;
            float cbx = (bl + br) * 0.5f, cby = (bt + bb) * 0.5f;
            float dx = cax - cbx, dy = cay - cby;
            float rho2 = dx * dx + dy * dy;
            float dat = atg - s_atanA[k];
            float v = 0.4052847345693511f * dat * dat;   // 4/pi^2
            float alp = v / (1.0f - iou + v + FEPS);
            float ciou = iou - rho2 / c2 - alp * v;
            int flat = j * 9 + k;
            if (ciou > bestv) { bestv = ciou; besti = flat; }
        }
        for (int off = 4; off; off >>= 1) {
            float ov = __shfl_down(bestv, off, 8);
            int   oi = __shfl_down(besti, off, 8);
            if (ov > bestv || (ov == bestv && oi < besti)) { bestv = ov; besti = oi; }
        }
        if (j == 0) {
            int mk = besti % 9;
            int layer = mk / 3;
            float f = FEATS_F[layer];
            float off_cr = s_cr[i][mk][1] * f + s_cr[i][mk][0];
            s_match[i] = (int)(LAYOFF_F[layer] + off_cr * 3.0f + (float)(mk - layer * 3));
        }
    }
    __syncthreads();

    if (l < 64) {
        const int i = l >> 3, j = l & 7;
        float sum = 0.0f;
        const int m = s_match[i];
        const float* prow = p + ((size_t)b * NA + (size_t)m) * 25;
        const int label = glabels[b * NBOX + i] - 1;
        for (int c = j; c < NCLS; c += 8) {
            float y = (c == label) ? 1.0f : 0.0f;
            sum += focal_term(prow[5 + c], y);
        }
        if (j == 0) {
            bool uniq = true;
            for (int jj = 0; jj < i; ++jj) if (s_match[jj] == m) uniq = false;
            if (uniq) {
                float x = prow[4];
                sum += focal_term(x, 1.0f) - focal0(x);
            }
            float s0 = 1.0f / (1.0f + expf(-prow[0]));
            float s1 = 1.0f / (1.0f + expf(-prow[1]));
            float px = s0 / fsz[2 * m]     + ancs[4 * m];
            float py = s1 / fsz[2 * m + 1] + ancs[4 * m + 1];
            float pw = expf(prow[2]) * ancs[4 * m + 2];
            float ph = expf(prow[3]) * ancs[4 * m + 3];
            float pl = px - pw * 0.5f, pt_ = py - ph * 0.5f;
            float pr = px + pw * 0.5f, pb = py + ph * 0.5f;
            float gl = s_g[i][0], gt = s_g[i][1], gr = s_g[i][2], gbb = s_g[i][3];
            float ix = fmaxf(fminf(gr, pr) - fmaxf(gl, pl), 0.0f);
            float iy = fmaxf(fminf(gbb, pb) - fmaxf(gt, pt_), 0.0f);
            float inter = ix * iy;
            float areaA = (gr - gl) * (gbb - gt);
            float areaB = (pr - pl) * (pb - pt_);
            float iou = inter / (areaA + areaB - inter + FEPS);
            float wbox = 2.0f - s_g[i][6] * s_g[i][7];
            sum += wbox * (1.0f - iou);
        }
        for (int off = 32; off; off >>= 1) sum += __shfl_down(sum, off);
        if (l == 0) atomicAdd(out, sum * scale);
    }
}

extern "C" void kernel_launch(void* const* d_in, const int* in_sizes, int n_in,
                              void* d_out, int out_size, void* d_ws, size_t ws_size,
                              hipStream_t stream) {
    const float* p      = (const float*)d_in[0];
    const float* gboxes = (const float*)d_in[1];
    const int*   glab   = (const int*)d_in[2];
    const float* ancs   = (const float*)d_in[3];
    const float* fsz    = (const float*)d_in[4];
    float* out = (float*)d_out;

    const int B    = in_sizes[0] / (NA * 25);     // 128
    const int ntot = B * NA;                      // 1362816
    const int S    = (ntot + 2) / 3;              // 454272 (exact /3 for B=128)
    const int CB   = (S + 255) / 256;             // 1775 conf blocks

    hipMemsetAsync(out, 0, sizeof(float), stream);
    hipLaunchKernelGGL(k_main, dim3(CB + B), dim3(256), 0, stream,
                       p, gboxes, glab, ancs, fsz, out, ntot, S, CB,
                       1.0f / (float)(NBOX * B));
}

// Round 4
// 44.591 us; speedup vs baseline: 1.1212x; 1.1212x over previous
//
#include <hip/hip_runtime.h>
#include <cstdint>
#include <cmath>

#define NA   10647
#define NBOX 8
#define NCLS 20
#define FEPS 1e-7f
#define CONF_BLOCKS 2048
#define T 256

__device__ __constant__ float ANC[9][2] = {
    {116.0f/416.0f,  90.0f/416.0f},
    {156.0f/416.0f, 198.0f/416.0f},
    {373.0f/416.0f, 326.0f/416.0f},
    { 30.0f/416.0f,  61.0f/416.0f},
    { 62.0f/416.0f,  45.0f/416.0f},
    { 59.0f/416.0f, 119.0f/416.0f},
    { 10.0f/416.0f,  13.0f/416.0f},
    { 16.0f/416.0f,  30.0f/416.0f},
    { 33.0f/416.0f,  23.0f/416.0f}};
__device__ __constant__ float FEATS_F[3] = {13.0f, 26.0f, 52.0f};
__device__ __constant__ float LAYOFF_F[3] = {0.0f, 507.0f, 2535.0f};

__device__ __forceinline__ float focal_term(float l, float y) {
    float bce = fmaxf(l, 0.0f) - l * y + log1pf(expf(-fabsf(l)));
    float p   = 1.0f / (1.0f + expf(-l));
    float pt  = y * p + (1.0f - y) * (1.0f - p);
    float af  = y * 0.25f + (1.0f - y) * 0.75f;
    float om  = 1.0f - pt;
    return bce * af * om * om;
}

// focal with y=0, one expf
__device__ __forceinline__ float focal0(float x) {
    float e   = expf(-fabsf(x));
    float bce = fmaxf(x, 0.0f) + log1pf(e);
    float inv = 1.0f / (1.0f + e);
    float p   = (x >= 0.0f) ? inv : e * inv;
    return bce * 0.75f * p * p;
}

// pick conf element from a float4 whose first float has channel c0 (valid c0 in [1,4])
__device__ __forceinline__ float pick_conf(const float4& v, unsigned c0) {
    return (c0 == 4u) ? v.x : (c0 == 3u) ? v.y : (c0 == 2u) ? v.z : v.w;
}

// -------- merged kernel: conf blocks [0,CONF_BLOCKS) + match blocks after ----
__global__ __launch_bounds__(T) void k_main(
    const float* __restrict__ p, const float* __restrict__ gboxes,
    const int* __restrict__ glabels, const float* __restrict__ ancs,
    const float* __restrict__ fsz, float* __restrict__ ws, long long n4)
{
    const int bid = blockIdx.x;

    if (bid < CONF_BLOCKS) {
        // ---- dense float4 stream, 4 independent loads per iteration ----
        const float4* p4 = (const float4*)p;
        const long long tid = (long long)bid * T + threadIdx.x;
        const long long nth = (long long)CONF_BLOCKS * T;       // 524288
        unsigned c = (unsigned)(((unsigned long long)tid * 4ull) % 25ull);
        const unsigned d = (unsigned)(((unsigned long long)nth * 4ull) % 25ull); // 2
        float acc = 0.0f;
        for (long long q = tid; q < n4; q += 4 * nth) {
            const long long q0 = q, q1 = q + nth, q2 = q + 2 * nth, q3 = q + 3 * nth;
            unsigned c0 = c;
            unsigned c1 = c0 + d; if (c1 >= 25u) c1 -= 25u;
            unsigned c2 = c1 + d; if (c2 >= 25u) c2 -= 25u;
            unsigned c3 = c2 + d; if (c3 >= 25u) c3 -= 25u;
            c = c3 + d; if (c >= 25u) c -= 25u;
            // issue all in-bounds loads first (independent), then math
            float4 v0, v1, v2, v3;
            bool b0 = (q0 < n4), b1 = (q1 < n4), b2 = (q2 < n4), b3 = (q3 < n4);
            if (b0) v0 = p4[q0];
            if (b1) v1 = p4[q1];
            if (b2) v2 = p4[q2];
            if (b3) v3 = p4[q3];
            if (b0 && c0 >= 1u && c0 <= 4u) acc += focal0(pick_conf(v0, c0));
            if (b1 && c1 >= 1u && c1 <= 4u) acc += focal0(pick_conf(v1, c1));
            if (b2 && c2 >= 1u && c2 <= 4u) acc += focal0(pick_conf(v2, c2));
            if (b3 && c3 >= 1u && c3 <= 4u) acc += focal0(pick_conf(v3, c3));
        }
        for (int off = 32; off; off >>= 1) acc += __shfl_down(acc, off);
        __shared__ float sred[4];
        if ((threadIdx.x & 63) == 0) sred[threadIdx.x >> 6] = acc;
        __syncthreads();
        if (threadIdx.x == 0)
            ws[bid] = sred[0] + sred[1] + sred[2] + sred[3];
        return;
    }

    // ---- per-image matching + cls/box/conf-correction (lanes 0..63 active) ----
    const int b = bid - CONF_BLOCKS;
    const int l = threadIdx.x;

    __shared__ float s_g[NBOX][9];
    __shared__ float s_anc[NBOX][9][4];
    __shared__ float s_cr[NBOX][9][2];
    __shared__ float s_atanA[9];
    __shared__ int   s_match[NBOX];

    if (l < NBOX) {
        const float* gb = gboxes + (size_t)(b * NBOX + l) * 4;
        float gl = gb[0], gt = gb[1], gr = gb[2], gbb = gb[3];
        float cx = (gl + gr) * 0.5f, cy = (gt + gbb) * 0.5f;
        float w = gr - gl, h = gbb - gt;
        s_g[l][0] = gl; s_g[l][1] = gt; s_g[l][2] = gr; s_g[l][3] = gbb;
        s_g[l][4] = cx; s_g[l][5] = cy; s_g[l][6] = w;  s_g[l][7] = h;
        s_g[l][8] = atanf(w / (h + FEPS));
    }
    if (l >= 64 && l < 64 + 9) s_atanA[l - 64] = atanf(ANC[l - 64][0] / (ANC[l - 64][1] + FEPS));
    if (l >= 128 && l < 128 + NBOX * 9) {
        int pair = l - 128;
        int j = pair / 9, k = pair % 9;
        const float* gb = gboxes + (size_t)(b * NBOX + j) * 4;
        float cx = (gb[0] + gb[2]) * 0.5f, cy = (gb[1] + gb[3]) * 0.5f;
        float fs = FEATS_F[k / 3];
        float col = floorf(cx * fs), row = floorf(cy * fs);
        float ax = col / fs, ay = row / fs;
        float aw = ANC[k][0], ah = ANC[k][1];
        s_anc[j][k][0] = ax - aw * 0.5f;
        s_anc[j][k][1] = ay - ah * 0.5f;
        s_anc[j][k][2] = ax + aw * 0.5f;
        s_anc[j][k][3] = ay + ah * 0.5f;
        s_cr[j][k][0] = col; s_cr[j][k][1] = row;
    }
    __syncthreads();

    if (l < 64) {
        const int i = l >> 3, j = l & 7;
        const float fi = (float)i, fj = (float)j;
        float al = s_g[i][0] + fi, at = s_g[i][1] + fi;
        float ar = s_g[i][2] + fi, ab = s_g[i][3] + fi;
        float wa = ar - al, ha = ab - at;
        float cax = (al + ar) * 0.5f, cay = (at + ab) * 0.5f;
        float atg = s_g[i][8];

        float bestv = -1e30f; int besti = 1 << 30;
        #pragma unroll
        for (int k = 0; k < 9; ++k) {
            float bl = s_anc[j][k][0] + fj, bt = s_anc[j][k][1] + fj;
            float br = s_anc[j][k][2] + fj, bb = s_anc[j][k][3] + fj;
            float wb = br - bl, hb = bb - bt;
            float ix = fmaxf(fminf(ar, br) - fmaxf(al, bl), 0.0f);
            float iy = fmaxf(fminf(ab, bb) - fmaxf(at, bt), 0.0f);
            float inter = ix * iy;
            float uni = wa * ha + wb * hb - inter;
            float iou = inter / (uni + FEPS);
            float cw = fmaxf(ar, br) - fminf(al, bl);
            float ch = fmaxf(ab, bb) - fminf(at, bt);
            float c2 = cw * cw + ch * ch + FEPS;
            float cbx = (bl + br) * 0.5f, cby = (bt + bb) * 0.5f;
            float dx = cax - cbx, dy = cay - cby;
            float rho2 = dx * dx + dy * dy;
            float dat = atg - s_atanA[k];
            float v = 0.4052847345693511f * dat * dat;   // 4/pi^2
            float alp = v / (1.0f - iou + v + FEPS);
            float ciou = iou - rho2 / c2 - alp * v;
            int flat = j * 9 + k;
            if (ciou > bestv) { bestv = ciou; besti = flat; }
        }
        for (int off = 4; off; off >>= 1) {
            float ov = __shfl_down(bestv, off, 8);
            int   oi = __shfl_down(besti, off, 8);
            if (ov > bestv || (ov == bestv && oi < besti)) { bestv = ov; besti = oi; }
        }
        if (j == 0) {
            int mk = besti % 9;
            int layer = mk / 3;
            float f = FEATS_F[layer];
            float off_cr = s_cr[i][mk][1] * f + s_cr[i][mk][0];
            s_match[i] = (int)(LAYOFF_F[layer] + off_cr * 3.0f + (float)(mk - layer * 3));
        }
    }
    __syncthreads();

    if (l < 64) {
        const int i = l >> 3, j = l & 7;
        float sum = 0.0f;
        const int m = s_match[i];
        const float* prow = p + ((size_t)b * NA + (size_t)m) * 25;
        const int label = glabels[b * NBOX + i] - 1;
        for (int c = j; c < NCLS; c += 8) {
            float y = (c == label) ? 1.0f : 0.0f;
            sum += focal_term(prow[5 + c], y);
        }
        if (j == 0) {
            bool uniq = true;
            for (int jj = 0; jj < i; ++jj) if (s_match[jj] == m) uniq = false;
            if (uniq) {
                float x = prow[4];
                sum += focal_term(x, 1.0f) - focal0(x);
            }
            float s0 = 1.0f / (1.0f + expf(-prow[0]));
            float s1 = 1.0f / (1.0f + expf(-prow[1]));
            float px = s0 / fsz[2 * m]     + ancs[4 * m];
            float py = s1 / fsz[2 * m + 1] + ancs[4 * m + 1];
            float pw = expf(prow[2]) * ancs[4 * m + 2];
            float ph = expf(prow[3]) * ancs[4 * m + 3];
            float pl = px - pw * 0.5f, pt_ = py - ph * 0.5f;
            float pr = px + pw * 0.5f, pb = py + ph * 0.5f;
            float gl = s_g[i][0], gt = s_g[i][1], gr = s_g[i][2], gbb = s_g[i][3];
            float ix = fmaxf(fminf(gr, pr) - fmaxf(gl, pl), 0.0f);
            float iy = fmaxf(fminf(gbb, pb) - fmaxf(gt, pt_), 0.0f);
            float inter = ix * iy;
            float areaA = (gr - gl) * (gbb - gt);
            float areaB = (pr - pl) * (pb - pt_);
            float iou = inter / (areaA + areaB - inter + FEPS);
            float wbox = 2.0f - s_g[i][6] * s_g[i][7];
            sum += wbox * (1.0f - iou);
        }
        for (int off = 32; off; off >>= 1) sum += __shfl_down(sum, off);
        if (l == 0) ws[CONF_BLOCKS + b] = sum;
    }
}

// ---------------- final deterministic reduction ------------------------------
__global__ __launch_bounds__(256) void k_final(const float* __restrict__ ws,
                                               float* __restrict__ out,
                                               int nslots, float scale)
{
    __shared__ float sred[256];
    float acc = 0.0f;
    for (int idx = threadIdx.x; idx < nslots; idx += 256) acc += ws[idx];
    sred[threadIdx.x] = acc;
    __syncthreads();
    for (int s = 128; s > 0; s >>= 1) {
        if (threadIdx.x < s) sred[threadIdx.x] += sred[threadIdx.x + s];
        __syncthreads();
    }
    if (threadIdx.x == 0) out[0] = sred[0] * scale;
}

extern "C" void kernel_launch(void* const* d_in, const int* in_sizes, int n_in,
                              void* d_out, int out_size, void* d_ws, size_t ws_size,
                              hipStream_t stream) {
    const float* p      = (const float*)d_in[0];
    const float* gboxes = (const float*)d_in[1];
    const int*   glab   = (const int*)d_in[2];
    const float* ancs   = (const float*)d_in[3];
    const float* fsz    = (const float*)d_in[4];
    float* out = (float*)d_out;
    float* ws  = (float*)d_ws;

    const int B = in_sizes[0] / (NA * 25);           // 128
    const long long n4 = (long long)in_sizes[0] / 4; // 8,517,600

    hipLaunchKernelGGL(k_main, dim3(CONF_BLOCKS + B), dim3(T), 0, stream,
                       p, gboxes, glab, ancs, fsz, ws, n4);
    hipLaunchKernelGGL(k_final, dim3(1), dim3(256), 0, stream,
                       ws, out, CONF_BLOCKS + B, 1.0f / (float)(NBOX * B));
}

// Round 5
// 33.491 us; speedup vs baseline: 1.4928x; 1.3314x over previous
//
#include <hip/hip_runtime.h>
#include <cstdint>
#include <cmath>

#define NA   10647
#define NBOX 8
#define NCLS 20
#define FEPS 1e-7f

__device__ __constant__ float ANC[9][2] = {
    {116.0f/416.0f,  90.0f/416.0f},
    {156.0f/416.0f, 198.0f/416.0f},
    {373.0f/416.0f, 326.0f/416.0f},
    { 30.0f/416.0f,  61.0f/416.0f},
    { 62.0f/416.0f,  45.0f/416.0f},
    { 59.0f/416.0f, 119.0f/416.0f},
    { 10.0f/416.0f,  13.0f/416.0f},
    { 16.0f/416.0f,  30.0f/416.0f},
    { 33.0f/416.0f,  23.0f/416.0f}};
__device__ __constant__ float FEATS_F[3] = {13.0f, 26.0f, 52.0f};
__device__ __constant__ float LAYOFF_F[3] = {0.0f, 507.0f, 2535.0f};

__device__ __forceinline__ float focal_term(float l, float y) {
    float bce = fmaxf(l, 0.0f) - l * y + log1pf(expf(-fabsf(l)));
    float p   = 1.0f / (1.0f + expf(-l));
    float pt  = y * p + (1.0f - y) * (1.0f - p);
    float af  = y * 0.25f + (1.0f - y) * 0.75f;
    float om  = 1.0f - pt;
    return bce * af * om * om;
}

// fast focal(y=0) on HW transcendentals: ~12 VALU instr
// t = x*log2e; u = 2^(-|t|) = e^{-|x|}; p = sigmoid(x); bce = ln2*(max(t,0)+log2(1+u))
__device__ __forceinline__ float focal0_fast(float x) {
    float t   = x * 1.442695040888963f;
    float u   = __builtin_amdgcn_exp2f(-fabsf(t));
    float opu = 1.0f + u;
    float inv = __builtin_amdgcn_rcpf(opu);
    float p   = (x >= 0.0f) ? inv : u * inv;
    float bce = 0.6931471805599453f * (fmaxf(t, 0.0f) + __builtin_amdgcn_logf(opu));
    return bce * 0.75f * p * p;
}

// -------------- merged kernel: conf blocks [0,CB) + match blocks [CB,CB+B) ---
__global__ __launch_bounds__(256) void k_main(
    const float* __restrict__ p, const float* __restrict__ gboxes,
    const int* __restrict__ glabels, const float* __restrict__ ancs,
    const float* __restrict__ fsz, float* __restrict__ ws,
    int ntot, int S, int conf_blocks)
{
    const int bid = blockIdx.x;

    if (bid < conf_blocks) {
        // ---- conf focal over all anchors (y=0 baseline), 3 anchors/thread ----
        const int tid = bid * 256 + threadIdx.x;
        float acc = 0.0f;
        if (tid < S) {
            const int i0 = tid, i1 = tid + S, i2 = tid + 2 * S;
            // issue all independent scalar loads first (conf channel = elem 25*i+4)
            float x0 = p[(size_t)i0 * 25 + 4];
            float x1 = (i1 < ntot) ? p[(size_t)i1 * 25 + 4] : 0.0f;
            float x2 = (i2 < ntot) ? p[(size_t)i2 * 25 + 4] : 0.0f;
            acc = focal0_fast(x0);
            if (i1 < ntot) acc += focal0_fast(x1);
            if (i2 < ntot) acc += focal0_fast(x2);
        }
        for (int off = 32; off; off >>= 1) acc += __shfl_down(acc, off);
        __shared__ float sred[4];
        if ((threadIdx.x & 63) == 0) sred[threadIdx.x >> 6] = acc;
        __syncthreads();
        if (threadIdx.x == 0)
            ws[bid] = sred[0] + sred[1] + sred[2] + sred[3];
        return;
    }

    // ---- per-image matching + cls/box/conf-correction (lanes 0..63 active) ----
    const int b = bid - conf_blocks;
    const int l = threadIdx.x;

    __shared__ float s_g[NBOX][9];        // l,t,r,b,cx,cy,w,h,atan(w/(h+eps))
    __shared__ float s_anc[NBOX][9][4];
    __shared__ float s_cr[NBOX][9][2];
    __shared__ float s_atanA[9];
    __shared__ int   s_match[NBOX];

    if (l < NBOX) {
        const float* gb = gboxes + (size_t)(b * NBOX + l) * 4;
        float gl = gb[0], gt = gb[1], gr = gb[2], gbb = gb[3];
        float cx = (gl + gr) * 0.5f, cy = (gt + gbb) * 0.5f;
        float w = gr - gl, h = gbb - gt;
        s_g[l][0] = gl; s_g[l][1] = gt; s_g[l][2] = gr; s_g[l][3] = gbb;
        s_g[l][4] = cx; s_g[l][5] = cy; s_g[l][6] = w;  s_g[l][7] = h;
        s_g[l][8] = atanf(w / (h + FEPS));
    }
    if (l >= 64 && l < 64 + 9) s_atanA[l - 64] = atanf(ANC[l - 64][0] / (ANC[l - 64][1] + FEPS));
    if (l >= 128 && l < 128 + NBOX * 9) {
        int pair = l - 128;
        int j = pair / 9, k = pair % 9;
        const float* gb = gboxes + (size_t)(b * NBOX + j) * 4;
        float cx = (gb[0] + gb[2]) * 0.5f, cy = (gb[1] + gb[3]) * 0.5f;
        float fs = FEATS_F[k / 3];
        float col = floorf(cx * fs), row = floorf(cy * fs);
        float ax = col / fs, ay = row / fs;
        float aw = ANC[k][0], ah = ANC[k][1];
        s_anc[j][k][0] = ax - aw * 0.5f;
        s_anc[j][k][1] = ay - ah * 0.5f;
        s_anc[j][k][2] = ax + aw * 0.5f;
        s_anc[j][k][3] = ay + ah * 0.5f;
        s_cr[j][k][0] = col; s_cr[j][k][1] = row;
    }
    __syncthreads();

    if (l < 64) {
        const int i = l >> 3, j = l & 7;
        const float fi = (float)i, fj = (float)j;
        float al = s_g[i][0] + fi, at = s_g[i][1] + fi;
        float ar = s_g[i][2] + fi, ab = s_g[i][3] + fi;
        float wa = ar - al, ha = ab - at;
        float cax = (al + ar) * 0.5f, cay = (at + ab) * 0.5f;
        float atg = s_g[i][8];

        float bestv = -1e30f; int besti = 1 << 30;
        #pragma unroll
        for (int k = 0; k < 9; ++k) {
            float bl = s_anc[j][k][0] + fj, bt = s_anc[j][k][1] + fj;
            float br = s_anc[j][k][2] + fj, bb = s_anc[j][k][3] + fj;
            float wb = br - bl, hb = bb - bt;
            float ix = fmaxf(fminf(ar, br) - fmaxf(al, bl), 0.0f);
            float iy = fmaxf(fminf(ab, bb) - fmaxf(at, bt), 0.0f);
            float inter = ix * iy;
            float uni = wa * ha + wb * hb - inter;
            float iou = inter / (uni + FEPS);
            float cw = fmaxf(ar, br) - fminf(al, bl);
            float ch = fmaxf(ab, bb) - fminf(at, bt);
            float c2 = cw * cw + ch * ch + FEPS;
            float cbx = (bl + br) * 0.5f, cby = (bt + bb) * 0.5f;
            float dx = cax - cbx, dy = cay - cby;
            float rho2 = dx * dx + dy * dy;
            float dat = atg - s_atanA[k];
            float v = 0.4052847345693511f * dat * dat;   // 4/pi^2
            float alp = v / (1.0f - iou + v + FEPS);
            float ciou = iou - rho2 / c2 - alp * v;
            int flat = j * 9 + k;
            if (ciou > bestv) { bestv = ciou; besti = flat; }
        }
        for (int off = 4; off; off >>= 1) {
            float ov = __shfl_down(bestv, off, 8);
            int   oi = __shfl_down(besti, off, 8);
            if (ov > bestv || (ov == bestv && oi < besti)) { bestv = ov; besti = oi; }
        }
        if (j == 0) {
            int mk = besti % 9;
            int layer = mk / 3;
            float f = FEATS_F[layer];
            float off_cr = s_cr[i][mk][1] * f + s_cr[i][mk][0];
            s_match[i] = (int)(LAYOFF_F[layer] + off_cr * 3.0f + (float)(mk - layer * 3));
        }
    }
    __syncthreads();

    if (l < 64) {
        const int i = l >> 3, j = l & 7;
        float sum = 0.0f;
        const int m = s_match[i];
        const float* prow = p + ((size_t)b * NA + (size_t)m) * 25;
        const int label = glabels[b * NBOX + i] - 1;
        for (int c = j; c < NCLS; c += 8) {
            float y = (c == label) ? 1.0f : 0.0f;
            sum += focal_term(prow[5 + c], y);
        }
        if (j == 0) {
            // conf correction: subtract exactly what the stream added (fast form)
            bool uniq = true;
            for (int jj = 0; jj < i; ++jj) if (s_match[jj] == m) uniq = false;
            if (uniq) {
                float x = prow[4];
                sum += focal_term(x, 1.0f) - focal0_fast(x);
            }
            float s0 = 1.0f / (1.0f + expf(-prow[0]));
            float s1 = 1.0f / (1.0f + expf(-prow[1]));
            float px = s0 / fsz[2 * m]     + ancs[4 * m];
            float py = s1 / fsz[2 * m + 1] + ancs[4 * m + 1];
            float pw = expf(prow[2]) * ancs[4 * m + 2];
            float ph = expf(prow[3]) * ancs[4 * m + 3];
            float pl = px - pw * 0.5f, pt_ = py - ph * 0.5f;
            float pr = px + pw * 0.5f, pb = py + ph * 0.5f;
            float gl = s_g[i][0], gt = s_g[i][1], gr = s_g[i][2], gbb = s_g[i][3];
            float ix = fmaxf(fminf(gr, pr) - fmaxf(gl, pl), 0.0f);
            float iy = fmaxf(fminf(gbb, pb) - fmaxf(gt, pt_), 0.0f);
            float inter = ix * iy;
            float areaA = (gr - gl) * (gbb - gt);
            float areaB = (pr - pl) * (pb - pt_);
            float iou = inter / (areaA + areaB - inter + FEPS);
            float wbox = 2.0f - s_g[i][6] * s_g[i][7];
            sum += wbox * (1.0f - iou);
        }
        for (int off = 32; off; off >>= 1) sum += __shfl_down(sum, off);
        if (l == 0) ws[conf_blocks + b] = sum;
    }
}

// ---------------- final deterministic reduction ------------------------------
__global__ __launch_bounds__(256) void k_final(const float* __restrict__ ws,
                                               float* __restrict__ out,
                                               int nslots, float scale)
{
    __shared__ float sred[256];
    float acc = 0.0f;
    for (int idx = threadIdx.x; idx < nslots; idx += 256) acc += ws[idx];
    sred[threadIdx.x] = acc;
    __syncthreads();
    for (int s = 128; s > 0; s >>= 1) {
        if (threadIdx.x < s) sred[threadIdx.x] += sred[threadIdx.x + s];
        __syncthreads();
    }
    if (threadIdx.x == 0) out[0] = sred[0] * scale;
}

extern "C" void kernel_launch(void* const* d_in, const int* in_sizes, int n_in,
                              void* d_out, int out_size, void* d_ws, size_t ws_size,
                              hipStream_t stream) {
    const float* p      = (const float*)d_in[0];
    const float* gboxes = (const float*)d_in[1];
    const int*   glab   = (const int*)d_in[2];
    const float* ancs   = (const float*)d_in[3];
    const float* fsz    = (const float*)d_in[4];
    float* out = (float*)d_out;
    float* ws  = (float*)d_ws;

    const int B    = in_sizes[0] / (NA * 25);     // 128
    const int ntot = B * NA;                      // 1362816
    const int S    = (ntot + 2) / 3;              // 454272 (exact /3 for B=128)
    const int CB   = (S + 255) / 256;             // 1775 conf blocks

    hipLaunchKernelGGL(k_main, dim3(CB + B), dim3(256), 0, stream,
                       p, gboxes, glab, ancs, fsz, ws, ntot, S, CB);
    hipLaunchKernelGGL(k_final, dim3(1), dim3(256), 0, stream,
                       ws, out, CB + B, 1.0f / (float)(NBOX * B));
}

// Round 6
// 32.618 us; speedup vs baseline: 1.5328x; 1.0268x over previous
//
#include <hip/hip_runtime.h>
#include <cstdint>
#include <cmath>

#define NA   10647
#define NBOX 8
#define NCLS 20
#define FEPS 1e-7f

__device__ __constant__ float ANC[9][2] = {
    {116.0f/416.0f,  90.0f/416.0f},
    {156.0f/416.0f, 198.0f/416.0f},
    {373.0f/416.0f, 326.0f/416.0f},
    { 30.0f/416.0f,  61.0f/416.0f},
    { 62.0f/416.0f,  45.0f/416.0f},
    { 59.0f/416.0f, 119.0f/416.0f},
    { 10.0f/416.0f,  13.0f/416.0f},
    { 16.0f/416.0f,  30.0f/416.0f},
    { 33.0f/416.0f,  23.0f/416.0f}};
__device__ __constant__ float FEATS_F[3] = {13.0f, 26.0f, 52.0f};
__device__ __constant__ float LAYOFF_F[3] = {0.0f, 507.0f, 2535.0f};

#define LOG2E 1.442695040888963f
#define LN2   0.6931471805599453f

// fast focal(y=0) on HW transcendentals (~12 VALU instr, no libcalls)
__device__ __forceinline__ float focal0_fast(float x) {
    float t   = x * LOG2E;
    float u   = __builtin_amdgcn_exp2f(-fabsf(t));
    float opu = 1.0f + u;
    float inv = __builtin_amdgcn_rcpf(opu);
    float p   = (x >= 0.0f) ? inv : u * inv;
    float bce = LN2 * (fmaxf(t, 0.0f) + __builtin_amdgcn_logf(opu));
    return bce * 0.75f * p * p;
}

// fast focal(y=1): bce = relu(-x)+log1p(e^{-|x|}); q = 1-sigmoid(x)
__device__ __forceinline__ float focal1_fast(float x) {
    float t   = x * LOG2E;
    float u   = __builtin_amdgcn_exp2f(-fabsf(t));
    float opu = 1.0f + u;
    float inv = __builtin_amdgcn_rcpf(opu);
    float q   = (x >= 0.0f) ? u * inv : inv;
    float bce = LN2 * (fmaxf(-t, 0.0f) + __builtin_amdgcn_logf(opu));
    return bce * 0.25f * q * q;
}

__device__ __forceinline__ float sigmoid_fast(float x) {
    float u = __builtin_amdgcn_exp2f(-fabsf(x) * LOG2E);
    float inv = __builtin_amdgcn_rcpf(1.0f + u);
    return (x >= 0.0f) ? inv : u * inv;
}

__device__ __forceinline__ float exp_fast(float x) {
    return __builtin_amdgcn_exp2f(x * LOG2E);
}

// -------------- merged kernel: conf blocks [0,CB) + match blocks [CB,CB+B) ---
// launch_bounds(256,8): cap VGPR<=64 so 8 blocks/CU reside -> ~18KB/CU in flight
__global__ __launch_bounds__(256, 8) void k_main(
    const float* __restrict__ p, const float* __restrict__ gboxes,
    const int* __restrict__ glabels, const float* __restrict__ ancs,
    const float* __restrict__ fsz, float* __restrict__ ws,
    int ntot, int S, int conf_blocks)
{
    const int bid = blockIdx.x;

    if (bid < conf_blocks) {
        // ---- conf focal over all anchors (y=0 baseline), 3 anchors/thread ----
        const int tid = bid * 256 + threadIdx.x;
        float acc = 0.0f;
        if (tid < S) {
            const int i0 = tid, i1 = tid + S, i2 = tid + 2 * S;
            float x0 = p[(size_t)i0 * 25 + 4];
            float x1 = (i1 < ntot) ? p[(size_t)i1 * 25 + 4] : 0.0f;
            float x2 = (i2 < ntot) ? p[(size_t)i2 * 25 + 4] : 0.0f;
            acc = focal0_fast(x0);
            if (i1 < ntot) acc += focal0_fast(x1);
            if (i2 < ntot) acc += focal0_fast(x2);
        }
        for (int off = 32; off; off >>= 1) acc += __shfl_down(acc, off);
        __shared__ float sred[4];
        if ((threadIdx.x & 63) == 0) sred[threadIdx.x >> 6] = acc;
        __syncthreads();
        if (threadIdx.x == 0)
            ws[bid] = sred[0] + sred[1] + sred[2] + sred[3];
        return;
    }

    // ---- per-image matching + cls/box/conf-correction (lanes 0..63 active) ----
    const int b = bid - conf_blocks;
    const int l = threadIdx.x;

    __shared__ float s_g[NBOX][9];        // l,t,r,b,cx,cy,w,h,atan(w/(h+eps))
    __shared__ float s_anc[NBOX][9][4];
    __shared__ float s_cr[NBOX][9][2];
    __shared__ float s_atanA[9];
    __shared__ int   s_match[NBOX];

    if (l < NBOX) {
        const float* gb = gboxes + (size_t)(b * NBOX + l) * 4;
        float gl = gb[0], gt = gb[1], gr = gb[2], gbb = gb[3];
        float cx = (gl + gr) * 0.5f, cy = (gt + gbb) * 0.5f;
        float w = gr - gl, h = gbb - gt;
        s_g[l][0] = gl; s_g[l][1] = gt; s_g[l][2] = gr; s_g[l][3] = gbb;
        s_g[l][4] = cx; s_g[l][5] = cy; s_g[l][6] = w;  s_g[l][7] = h;
        s_g[l][8] = atanf(w / (h + FEPS));
    }
    if (l >= 64 && l < 64 + 9) s_atanA[l - 64] = atanf(ANC[l - 64][0] / (ANC[l - 64][1] + FEPS));
    if (l >= 128 && l < 128 + NBOX * 9) {
        int pair = l - 128;
        int j = pair / 9, k = pair % 9;
        const float* gb = gboxes + (size_t)(b * NBOX + j) * 4;
        float cx = (gb[0] + gb[2]) * 0.5f, cy = (gb[1] + gb[3]) * 0.5f;
        float fs = FEATS_F[k / 3];
        float col = floorf(cx * fs), row = floorf(cy * fs);
        float ax = col / fs, ay = row / fs;
        float aw = ANC[k][0], ah = ANC[k][1];
        s_anc[j][k][0] = ax - aw * 0.5f;
        s_anc[j][k][1] = ay - ah * 0.5f;
        s_anc[j][k][2] = ax + aw * 0.5f;
        s_anc[j][k][3] = ay + ah * 0.5f;
        s_cr[j][k][0] = col; s_cr[j][k][1] = row;
    }
    __syncthreads();

    if (l < 64) {
        const int i = l >> 3, j = l & 7;
        const float fi = (float)i, fj = (float)j;
        float al = s_g[i][0] + fi, at = s_g[i][1] + fi;
        float ar = s_g[i][2] + fi, ab = s_g[i][3] + fi;
        float wa = ar - al, ha = ab - at;
        float cax = (al + ar) * 0.5f, cay = (at + ab) * 0.5f;
        float atg = s_g[i][8];

        float bestv = -1e30f; int besti = 1 << 30;
        #pragma unroll
        for (int k = 0; k < 9; ++k) {
            float bl = s_anc[j][k][0] + fj, bt = s_anc[j][k][1] + fj;
            float br = s_anc[j][k][2] + fj, bb = s_anc[j][k][3] + fj;
            float wb = br - bl, hb = bb - bt;
            float ix = fmaxf(fminf(ar, br) - fmaxf(al, bl), 0.0f);
            float iy = fmaxf(fminf(ab, bb) - fmaxf(at, bt), 0.0f);
            float inter = ix * iy;
            float uni = wa * ha + wb * hb - inter;
            float iou = inter / (uni + FEPS);
            float cw = fmaxf(ar, br) - fminf(al, bl);
            float ch = fmaxf(ab, bb) - fminf(at, bt);
            float c2 = cw * cw + ch * ch + FEPS;
            float cbx = (bl + br) * 0.5f, cby = (bt + bb) * 0.5f;
            float dx = cax - cbx, dy = cay - cby;
            float rho2 = dx * dx + dy * dy;
            float dat = atg - s_atanA[k];
            float v = 0.4052847345693511f * dat * dat;   // 4/pi^2
            float alp = v / (1.0f - iou + v + FEPS);
            float ciou = iou - rho2 / c2 - alp * v;
            int flat = j * 9 + k;
            if (ciou > bestv) { bestv = ciou; besti = flat; }
        }
        for (int off = 4; off; off >>= 1) {
            float ov = __shfl_down(bestv, off, 8);
            int   oi = __shfl_down(besti, off, 8);
            if (ov > bestv || (ov == bestv && oi < besti)) { bestv = ov; besti = oi; }
        }
        if (j == 0) {
            int mk = besti % 9;
            int layer = mk / 3;
            float f = FEATS_F[layer];
            float off_cr = s_cr[i][mk][1] * f + s_cr[i][mk][0];
            s_match[i] = (int)(LAYOFF_F[layer] + off_cr * 3.0f + (float)(mk - layer * 3));
        }
    }
    __syncthreads();

    if (l < 64) {
        const int i = l >> 3, j = l & 7;
        float sum = 0.0f;
        const int m = s_match[i];
        const float* prow = p + ((size_t)b * NA + (size_t)m) * 25;
        const int label = glabels[b * NBOX + i] - 1;
        for (int c = j; c < NCLS; c += 8) {
            float x = prow[5 + c];
            sum += (c == label) ? focal1_fast(x) : focal0_fast(x);
        }
        if (j == 0) {
            // conf correction: subtract exactly what the stream added (fast form)
            bool uniq = true;
            for (int jj = 0; jj < i; ++jj) if (s_match[jj] == m) uniq = false;
            if (uniq) {
                float x = prow[4];
                sum += focal1_fast(x) - focal0_fast(x);
            }
            float s0 = sigmoid_fast(prow[0]);
            float s1 = sigmoid_fast(prow[1]);
            float px = s0 / fsz[2 * m]     + ancs[4 * m];
            float py = s1 / fsz[2 * m + 1] + ancs[4 * m + 1];
            float pw = exp_fast(prow[2]) * ancs[4 * m + 2];
            float ph = exp_fast(prow[3]) * ancs[4 * m + 3];
            float pl = px - pw * 0.5f, pt_ = py - ph * 0.5f;
            float pr = px + pw * 0.5f, pb = py + ph * 0.5f;
            float gl = s_g[i][0], gt = s_g[i][1], gr = s_g[i][2], gbb = s_g[i][3];
            float ix = fmaxf(fminf(gr, pr) - fmaxf(gl, pl), 0.0f);
            float iy = fmaxf(fminf(gbb, pb) - fmaxf(gt, pt_), 0.0f);
            float inter = ix * iy;
            float areaA = (gr - gl) * (gbb - gt);
            float areaB = (pr - pl) * (pb - pt_);
            float iou = inter / (areaA + areaB - inter + FEPS);
            float wbox = 2.0f - s_g[i][6] * s_g[i][7];
            sum += wbox * (1.0f - iou);
        }
        for (int off = 32; off; off >>= 1) sum += __shfl_down(sum, off);
        if (l == 0) ws[conf_blocks + b] = sum;
    }
}

// ---------------- final deterministic reduction ------------------------------
__global__ __launch_bounds__(256) void k_final(const float* __restrict__ ws,
                                               float* __restrict__ out,
                                               int nslots, float scale)
{
    __shared__ float sred[256];
    float acc = 0.0f;
    for (int idx = threadIdx.x; idx < nslots; idx += 256) acc += ws[idx];
    sred[threadIdx.x] = acc;
    __syncthreads();
    for (int s = 128; s > 0; s >>= 1) {
        if (threadIdx.x < s) sred[threadIdx.x] += sred[threadIdx.x + s];
        __syncthreads();
    }
    if (threadIdx.x == 0) out[0] = sred[0] * scale;
}

extern "C" void kernel_launch(void* const* d_in, const int* in_sizes, int n_in,
                              void* d_out, int out_size, void* d_ws, size_t ws_size,
                              hipStream_t stream) {
    const float* p      = (const float*)d_in[0];
    const float* gboxes = (const float*)d_in[1];
    const int*   glab   = (const int*)d_in[2];
    const float* ancs   = (const float*)d_in[3];
    const float* fsz    = (const float*)d_in[4];
    float* out = (float*)d_out;
    float* ws  = (float*)d_ws;

    const int B    = in_sizes[0] / (NA * 25);     // 128
    const int ntot = B * NA;                      // 1362816
    const int S    = (ntot + 2) / 3;              // 454272 (exact /3 for B=128)
    const int CB   = (S + 255) / 256;             // 1775 conf blocks

    hipLaunchKernelGGL(k_main, dim3(CB + B), dim3(256), 0, stream,
                       p, gboxes, glab, ancs, fsz, ws, ntot, S, CB);
    hipLaunchKernelGGL(k_final, dim3(1), dim3(256), 0, stream,
                       ws, out, CB + B, 1.0f / (float)(NBOX * B));
}